// Round 8
// baseline (86.728 us; speedup 1.0000x reference)
//
#include <hip/hip_runtime.h>

#define D 32
#define T 2049
#define NH 2
#define NBLK 257          // 257 * 8 = 2056 >= 2049 columns
#define PAD 33            // LDS row pad: (k*33+d)%32 hits distinct banks

typedef unsigned long long u64;

// ---------------------------------------------------------------------------
// Exact-sign-signature formulation (verified R3/R7, absmax 0.0):
// attn[l,j] = 1 iff 32-bit sign signature of (B@Z)[:,l] equals that of
// (C@Z)[:,j]; bit k = x[k] > 0, bit 32 = any exact zero (never matches /
// kills the column). Expected matches ~ 2*2049^2/2^32 ~ 0.002 -> output is
// the residual passthrough; rare path recomputes V@Z[:,l] exactly on match.
//
// Pipeline (3 kernels; grid.sync measured 40+ us/sync on this chip, R6):
//   K1 sig0:      layer-0 sigs from Z
//   K2 attn+sig1: Zmid = Z + attn0; layer-1 sigs from in-LDS Zmid
//   K3 attn:      out  = Zmid + attn1
// R8 change: attn scan split across the 4 waves (512-source stripe each,
// all 8 block columns per wave) -> 1 memory-latency round instead of 8,
// 4x less sig traffic; LDS reduction of (rare) partial sums.
// ---------------------------------------------------------------------------

__device__ __forceinline__ void sig_from_lds(
    const float (*Bs)[32][PAD], const float (*Cs)[32][PAD],
    const float* Zcol,           // 32 floats in LDS (broadcast reads)
    int tid, int t,
    u64* __restrict__ sigU, u64* __restrict__ sigW)
{
    const int k = tid & 31;
    #pragma unroll
    for (int h = 0; h < NH; ++h) {
        float u = 0.f, w = 0.f;
        #pragma unroll
        for (int d = 0; d < 32; ++d) {
            float z = Zcol[d];
            u += Bs[h][k][d] * z;
            w += Cs[h][k][d] * z;
        }
        u64 pu = __ballot(u > 0.0f);
        u64 zu = __ballot(u == 0.0f);
        u64 pw = __ballot(w > 0.0f);
        u64 zw = __ballot(w == 0.0f);
        const int wid = tid & 63;
        if ((wid == 0 || wid == 32) && t < T) {
            const int sh = (wid == 0) ? 0 : 32;
            u64 su = (unsigned int)(pu >> sh);
            if ((unsigned int)(zu >> sh)) su |= (1ull << 32);
            u64 sw = (unsigned int)(pw >> sh);
            if ((unsigned int)(zw >> sh)) sw |= (1ull << 32);
            sigU[h * T + t] = su;
            sigW[h * T + t] = sw;
        }
    }
}

// ---------------- K1: layer-0 signatures ------------------------------------
__global__ __launch_bounds__(256) void sig0_kernel(
    const float* __restrict__ Z, const float* __restrict__ allparam,
    u64* __restrict__ sigU, u64* __restrict__ sigW)
{
    const int tid = threadIdx.x, b = blockIdx.x;
    __shared__ float Bs[NH][32][PAD];
    __shared__ float Cs[NH][32][PAD];
    __shared__ float Zs[8][32];

    #pragma unroll
    for (int h = 0; h < NH; ++h) {
        const float* Bp = allparam + (h * 3 + 1) * 1024;
        const float* Cp = allparam + (h * 3 + 2) * 1024;
        #pragma unroll
        for (int i = 0; i < 4; ++i) {
            int idx = tid + 256 * i;
            Bs[h][idx >> 5][idx & 31] = Bp[idx];
            Cs[h][idx >> 5][idx & 31] = Cp[idx];
        }
    }
    {
        int d = tid >> 3, c = tid & 7;
        int t = b * 8 + c; if (t >= T) t = T - 1;
        Zs[c][d] = Z[d * T + t];
    }
    __syncthreads();

    const int c = tid >> 5;
    sig_from_lds(Bs, Cs, Zs[c], tid, b * 8 + c, sigU, sigW);
}

// ---------------- wave-split attn scan for a block's 8 columns --------------
// Each wave w covers sources [w*512, (w+1)*512) for ALL 8 columns; partial
// sums land in accs[w][c][k]; caller reduces after __syncthreads().
__device__ __forceinline__ void attn_scan_block(
    const float* __restrict__ Zin, const float* __restrict__ pbase,
    const u64* __restrict__ sigU, const u64* __restrict__ sigW,
    int b, int tid, float (*accs)[8][32])
{
    const int w = tid >> 6, lane = tid & 63, k = lane & 31;
    float acc[8] = {0.f,0.f,0.f,0.f,0.f,0.f,0.f,0.f};

    // prefetch both heads' sig stripe: 16 loads, one latency round
    u64 sv0[8], sv1[8];
    #pragma unroll
    for (int q = 0; q < 8; ++q) sv0[q] = sigU[0 * T + w * 512 + q * 64 + lane];
    #pragma unroll
    for (int q = 0; q < 8; ++q) sv1[q] = sigU[1 * T + w * 512 + q * 64 + lane];

    #pragma unroll
    for (int h = 0; h < NH; ++h) {
        const u64* sv = h ? sv1 : sv0;
        const float* V = pbase + h * 3 * 1024;
        u64 wv[8]; bool alive[8];
        #pragma unroll
        for (int c = 0; c < 8; ++c) {
            int j = b * 8 + c;
            wv[c] = (j < T) ? sigW[h * T + j] : ~0ull;
            alive[c] = ((wv[c] >> 32) == 0);      // wave-uniform
        }
        #pragma unroll
        for (int q = 0; q < 8; ++q) {
            #pragma unroll
            for (int c = 0; c < 8; ++c) {
                if (!alive[c]) continue;          // uniform branch
                u64 m = __ballot(sv[q] == wv[c]);
                while (m) {                       // rare exact path
                    const int bb = __builtin_ctzll(m); m &= m - 1;
                    const int lm = w * 512 + q * 64 + bb;
                    float kv = 0.f;
                    #pragma unroll
                    for (int d = 0; d < 32; ++d)
                        kv += V[k * 32 + d] * Zin[d * T + lm];
                    acc[c] += kv;                 // halves duplicate; ok
                }
            }
        }
    }
    if (lane < 32) {
        #pragma unroll
        for (int c = 0; c < 8; ++c) accs[w][c][k] = acc[c];
    }
}

// ---------------- K2: attn layer 0 + signatures layer 1 ---------------------
__global__ __launch_bounds__(256) void attn_sig_kernel(
    const float* __restrict__ Zin, const float* __restrict__ allparam,
    const u64* __restrict__ sig0U, const u64* __restrict__ sig0W,
    u64* __restrict__ sig1U, u64* __restrict__ sig1W,
    float* __restrict__ Zout)
{
    const int tid = threadIdx.x, b = blockIdx.x;
    __shared__ float Bs[NH][32][PAD];   // layer-1 B
    __shared__ float Cs[NH][32][PAD];   // layer-1 C
    __shared__ float Zs[8][32];         // fresh Zmid columns
    __shared__ float accs[4][8][32];

    // stage layer-1 B,C (loads overlap the scan; resolved at the barrier)
    const float* p1 = allparam + NH * 3 * 1024;
    #pragma unroll
    for (int h = 0; h < NH; ++h) {
        const float* Bp = p1 + (h * 3 + 1) * 1024;
        const float* Cp = p1 + (h * 3 + 2) * 1024;
        #pragma unroll
        for (int i = 0; i < 4; ++i) {
            int idx = tid + 256 * i;
            Bs[h][idx >> 5][idx & 31] = Bp[idx];
            Cs[h][idx >> 5][idx & 31] = Cp[idx];
        }
    }

    attn_scan_block(Zin, allparam, sig0U, sig0W, b, tid, accs);
    __syncthreads();

    // reduce 4 waves, add residual, write Zmid, stage column in LDS
    const int c = tid >> 5, k = tid & 31;
    const int j = b * 8 + c;
    float r = 0.f;
    if (j < T) {
        r = Zin[k * T + j]
          + accs[0][c][k] + accs[1][c][k] + accs[2][c][k] + accs[3][c][k];
        Zout[k * T + j] = r;
    }
    Zs[c][k] = r;
    __syncthreads();

    sig_from_lds(Bs, Cs, Zs[c], tid, j, sig1U, sig1W);
}

// ---------------- K3: attn layer 1 ------------------------------------------
__global__ __launch_bounds__(256) void attn_kernel(
    const float* __restrict__ Zin, const float* __restrict__ allparam,
    const u64* __restrict__ sigU, const u64* __restrict__ sigW,
    float* __restrict__ Zout)
{
    const int tid = threadIdx.x, b = blockIdx.x;
    __shared__ float accs[4][8][32];
    const float* p1 = allparam + NH * 3 * 1024;   // layer-1 params

    attn_scan_block(Zin, p1, sigU, sigW, b, tid, accs);
    __syncthreads();

    const int c = tid >> 5, k = tid & 31;
    const int j = b * 8 + c;
    if (j < T) {
        float r = Zin[k * T + j]
          + accs[0][c][k] + accs[1][c][k] + accs[2][c][k] + accs[3][c][k];
        Zout[k * T + j] = r;
    }
}

extern "C" void kernel_launch(void* const* d_in, const int* in_sizes, int n_in,
                              void* d_out, int out_size, void* d_ws, size_t ws_size,
                              hipStream_t stream) {
    const float* Z        = (const float*)d_in[0];   // (32, 2049) f32
    const float* allparam = (const float*)d_in[1];   // (2,2,3,32,32) f32
    float* out            = (float*)d_out;

    // workspace layout
    float* Zmid = (float*)d_ws;                                    // 32*2049 f32
    size_t off = ((size_t)D * T * sizeof(float) + 255) & ~(size_t)255;
    u64* sig0U = (u64*)((char*)d_ws + off);
    u64* sig0W = sig0U + (size_t)NH * T;
    u64* sig1U = sig0W + (size_t)NH * T;
    u64* sig1W = sig1U + (size_t)NH * T;

    sig0_kernel<<<NBLK, 256, 0, stream>>>(Z, allparam, sig0U, sig0W);
    attn_sig_kernel<<<NBLK, 256, 0, stream>>>(Z, allparam, sig0U, sig0W,
                                              sig1U, sig1W, Zmid);
    attn_kernel<<<NBLK, 256, 0, stream>>>(Zmid, allparam, sig1U, sig1W, out);
}

// Round 10
// 74.777 us; speedup vs baseline: 1.1598x; 1.1598x over previous
//
#include <hip/hip_runtime.h>

#define D 32
#define T 2049
#define NH 2
#define NBLK 257          // 257 * 8 = 2056 >= 2049 columns
#define PAD 33            // LDS row pad: (k*33+d)%32 hits distinct banks

typedef unsigned long long u64;

// ---------------------------------------------------------------------------
// Exact-sign-signature formulation (verified R3/R7, absmax 0.0):
// attn[l,j] = 1 iff 32-bit sign signature of (B@Z)[:,l] equals that of
// (C@Z)[:,j]; bit k = x[k] > 0, bit 32 = any exact zero (never matches /
// kills the column). Expected matches ~ 2*2049^2/2^32 ~ 0.002 -> output is
// the residual passthrough; rare path recomputes V@Z[:,l] exactly on match.
//
// Pipeline (3 kernels; grid.sync measured 30-40 us/sync on this chip, R6;
// wave-split scan measured +12 us, R8 — this is the measured-best R7 form):
//   K1 sig0:      layer-0 sigs from Z
//   K2 attn+sig1: Zmid = Z + attn0; layer-1 sigs from in-LDS Zmid
//   K3 attn:      out  = Zmid + attn1
// ---------------------------------------------------------------------------

__device__ __forceinline__ void sig_from_lds(
    const float (*Bs)[32][PAD], const float (*Cs)[32][PAD],
    const float* Zcol,           // LDS column (32 floats, broadcast reads)
    int tid, int t,
    u64* __restrict__ sigU, u64* __restrict__ sigW)
{
    const int k = tid & 31;
    #pragma unroll
    for (int h = 0; h < NH; ++h) {
        float u = 0.f, w = 0.f;
        #pragma unroll
        for (int d = 0; d < 32; ++d) {
            float z = Zcol[d];
            u += Bs[h][k][d] * z;
            w += Cs[h][k][d] * z;
        }
        u64 pu = __ballot(u > 0.0f);
        u64 zu = __ballot(u == 0.0f);
        u64 pw = __ballot(w > 0.0f);
        u64 zw = __ballot(w == 0.0f);
        const int wid = tid & 63;
        if ((wid == 0 || wid == 32) && t < T) {
            const int sh = (wid == 0) ? 0 : 32;
            u64 su = (unsigned int)(pu >> sh);
            if ((unsigned int)(zu >> sh)) su |= (1ull << 32);
            u64 sw = (unsigned int)(pw >> sh);
            if ((unsigned int)(zw >> sh)) sw |= (1ull << 32);
            sigU[h * T + t] = su;
            sigW[h * T + t] = sw;
        }
    }
}

// ---------------- K1: layer-0 signatures ------------------------------------
__global__ __launch_bounds__(256) void sig0_kernel(
    const float* __restrict__ Z, const float* __restrict__ allparam,
    u64* __restrict__ sigU, u64* __restrict__ sigW)
{
    const int tid = threadIdx.x, b = blockIdx.x;
    __shared__ float Bs[NH][32][PAD];
    __shared__ float Cs[NH][32][PAD];
    __shared__ float Zs[8][32];

    #pragma unroll
    for (int h = 0; h < NH; ++h) {
        const float* Bp = allparam + (h * 3 + 1) * 1024;
        const float* Cp = allparam + (h * 3 + 2) * 1024;
        #pragma unroll
        for (int i = 0; i < 4; ++i) {
            int idx = tid + 256 * i;
            Bs[h][idx >> 5][idx & 31] = Bp[idx];
            Cs[h][idx >> 5][idx & 31] = Cp[idx];
        }
    }
    {
        int d = tid >> 3, c = tid & 7;
        int t = b * 8 + c; if (t >= T) t = T - 1;
        Zs[c][d] = Z[d * T + t];
    }
    __syncthreads();

    const int c = tid >> 5;
    sig_from_lds(Bs, Cs, Zs[c], tid, b * 8 + c, sigU, sigW);
}

// ---------------- attn scan for one wave's two columns ----------------------
__device__ __forceinline__ void attn_scan(
    const float* __restrict__ Zin, const float* __restrict__ pbase,
    const u64* __restrict__ sigU, const u64* __restrict__ sigW,
    int j0, int j1, int lane, int k, float& acc0, float& acc1)
{
    #pragma unroll
    for (int h = 0; h < NH; ++h) {
        u64 wv0 = (j0 < T) ? sigW[h * T + j0] : ~0ull;
        u64 wv1 = (j1 < T) ? sigW[h * T + j1] : ~0ull;
        const bool s0 = (wv0 >> 32) != 0;   // zero-flag -> dead column
        const bool s1 = (wv1 >> 32) != 0;
        if (s0 && s1) continue;             // wave-uniform
        const float* V = pbase + h * 3 * 1024;
        const u64* su = sigU + h * T;
        for (int it0 = 0; it0 < 32; it0 += 8) {   // 32*64 = 2048 = T-1 sources
            u64 sv[8];
            #pragma unroll
            for (int q = 0; q < 8; ++q)           // prefetch: 1 wait per 8 loads
                sv[q] = su[(it0 + q) * 64 + lane];
            #pragma unroll
            for (int q = 0; q < 8; ++q) {
                u64 m0 = __ballot(!s0 && sv[q] == wv0);
                u64 m1 = __ballot(!s1 && sv[q] == wv1);
                while (m0) {                      // rare exact path
                    const int bb = __builtin_ctzll(m0); m0 &= m0 - 1;
                    const int lm = (it0 + q) * 64 + bb;
                    float kv = 0.f;
                    #pragma unroll
                    for (int d = 0; d < 32; ++d)
                        kv += V[k * 32 + d] * Zin[d * T + lm];
                    acc0 += kv;
                }
                while (m1) {
                    const int bb = __builtin_ctzll(m1); m1 &= m1 - 1;
                    const int lm = (it0 + q) * 64 + bb;
                    float kv = 0.f;
                    #pragma unroll
                    for (int d = 0; d < 32; ++d)
                        kv += V[k * 32 + d] * Zin[d * T + lm];
                    acc1 += kv;
                }
            }
        }
    }
}

// ---------------- K2: attn layer 0 + signatures layer 1 ---------------------
__global__ __launch_bounds__(256) void attn_sig_kernel(
    const float* __restrict__ Zin, const float* __restrict__ allparam,
    const u64* __restrict__ sig0U, const u64* __restrict__ sig0W,
    u64* __restrict__ sig1U, u64* __restrict__ sig1W,
    float* __restrict__ Zout)
{
    const int tid = threadIdx.x, b = blockIdx.x;
    const int w = tid >> 6, lane = tid & 63, k = lane & 31, half = lane >> 5;
    const int j0 = b * 8 + w * 2, j1 = j0 + 1;

    __shared__ float Bs[NH][32][PAD];   // layer-1 B
    __shared__ float Cs[NH][32][PAD];   // layer-1 C
    __shared__ float Zs[8][32];         // fresh Zmid columns

    // stage layer-1 B,C (overlaps with attn below; waits resolved at barrier)
    const float* p1 = allparam + NH * 3 * 1024;
    #pragma unroll
    for (int h = 0; h < NH; ++h) {
        const float* Bp = p1 + (h * 3 + 1) * 1024;
        const float* Cp = p1 + (h * 3 + 2) * 1024;
        #pragma unroll
        for (int i = 0; i < 4; ++i) {
            int idx = tid + 256 * i;
            Bs[h][idx >> 5][idx & 31] = Bp[idx];
            Cs[h][idx >> 5][idx & 31] = Cp[idx];
        }
    }

    // attn layer 0 for columns j0, j1
    float acc0 = 0.f, acc1 = 0.f;
    attn_scan(Zin, allparam, sig0U, sig0W, j0, j1, lane, k, acc0, acc1);

    // residual add, write Zmid, stage fresh column into LDS
    const int jc   = half ? j1 : j0;
    const float ac = half ? acc1 : acc0;
    float r = 0.f;
    if (jc < T) {
        r = Zin[k * T + jc] + ac;
        Zout[k * T + jc] = r;
    }
    Zs[w * 2 + half][k] = r;
    __syncthreads();

    // layer-1 signatures from in-register/LDS Zmid columns
    const int c = tid >> 5;   // == w*2 + half
    sig_from_lds(Bs, Cs, Zs[c], tid, b * 8 + c, sig1U, sig1W);
}

// ---------------- K3: attn layer 1 ------------------------------------------
__global__ __launch_bounds__(256) void attn_kernel(
    const float* __restrict__ Zin, const float* __restrict__ allparam,
    const u64* __restrict__ sigU, const u64* __restrict__ sigW,
    float* __restrict__ Zout)
{
    const int tid = threadIdx.x, b = blockIdx.x;
    const int w = tid >> 6, lane = tid & 63, k = lane & 31, half = lane >> 5;
    const int j0 = b * 8 + w * 2, j1 = j0 + 1;
    const float* p1 = allparam + NH * 3 * 1024;   // layer 1 params

    float acc0 = 0.f, acc1 = 0.f;
    attn_scan(Zin, p1, sigU, sigW, j0, j1, lane, k, acc0, acc1);

    const int jc   = half ? j1 : j0;
    const float ac = half ? acc1 : acc0;
    if (jc < T) Zout[k * T + jc] = Zin[k * T + jc] + ac;
}

extern "C" void kernel_launch(void* const* d_in, const int* in_sizes, int n_in,
                              void* d_out, int out_size, void* d_ws, size_t ws_size,
                              hipStream_t stream) {
    const float* Z        = (const float*)d_in[0];   // (32, 2049) f32
    const float* allparam = (const float*)d_in[1];   // (2,2,3,32,32) f32
    float* out            = (float*)d_out;

    // workspace layout
    float* Zmid = (float*)d_ws;                                    // 32*2049 f32
    size_t off = ((size_t)D * T * sizeof(float) + 255) & ~(size_t)255;
    u64* sig0U = (u64*)((char*)d_ws + off);
    u64* sig0W = sig0U + (size_t)NH * T;
    u64* sig1U = sig0W + (size_t)NH * T;
    u64* sig1W = sig1U + (size_t)NH * T;

    sig0_kernel<<<NBLK, 256, 0, stream>>>(Z, allparam, sig0U, sig0W);
    attn_sig_kernel<<<NBLK, 256, 0, stream>>>(Z, allparam, sig0U, sig0W,
                                              sig1U, sig1W, Zmid);
    attn_kernel<<<NBLK, 256, 0, stream>>>(Zmid, allparam, sig1U, sig1W, out);
}